// Round 7
// baseline (126.700 us; speedup 1.0000x reference)
//
#include <hip/hip_runtime.h>
#include <math.h>

#define N_TOTAL 8192
#define BHALF   4096
#define KDIM    128
#define NTILES  64                            // 8192 / 128
#define NBLK    (NTILES * (NTILES + 1) / 2)   // 2080 triangular tiles

typedef __bf16 bf16x8 __attribute__((ext_vector_type(8)));
typedef __bf16 bf16x2 __attribute__((ext_vector_type(2)));
typedef float  f32x4  __attribute__((ext_vector_type(4)));

// ---------------------------------------------------------------------------
// Kernel A (fused prep+pos): one wave per pair (i, i+BHALF).
//  fp32 sq-norms (exact), bf16 copy of both rows,
//  per-block positive-pair partial -> posPart[block] (plain store).
// ---------------------------------------------------------------------------
__global__ __launch_bounds__(256) void k_prep_pos(const float* __restrict__ F,
                                                  __bf16* __restrict__ Fbf,
                                                  float* __restrict__ sq,
                                                  float* __restrict__ posPart) {
    int t = threadIdx.x;
    int w = t >> 6, l = t & 63;
    int p = blockIdx.x * 4 + w;          // pair index 0..4095
    const float2* r1 = (const float2*)(F + (size_t)p * KDIM);
    const float2* r2 = (const float2*)(F + (size_t)(p + BHALF) * KDIM);
    float2 a = r1[l];
    float2 c = r2[l];

    float s1 = fmaf(a.x, a.x, a.y * a.y);
    float s2 = fmaf(c.x, c.x, c.y * c.y);
    float dp = fmaf(a.x, c.x, a.y * c.y);
#pragma unroll
    for (int off = 32; off > 0; off >>= 1) {
        s1 += __shfl_down(s1, off);
        s2 += __shfl_down(s2, off);
        dp += __shfl_down(dp, off);
    }

    bf16x2 pa, pc;
    pa[0] = (__bf16)a.x; pa[1] = (__bf16)a.y;
    pc[0] = (__bf16)c.x; pc[1] = (__bf16)c.y;
    ((bf16x2*)(Fbf + (size_t)p * KDIM))[l] = pa;
    ((bf16x2*)(Fbf + (size_t)(p + BHALF) * KDIM))[l] = pc;

    __shared__ float posRed[4];
    if (l == 0) {
        sq[p] = s1;
        sq[p + BHALF] = s2;
        float d2 = fmaxf(s1 + s2 - 2.0f * dp, 0.0f);
        posRed[w] = logf(1.0f + d2);
    }
    __syncthreads();
    if (t == 0)
        posPart[blockIdx.x] = posRed[0] + posRed[1] + posRed[2] + posRed[3];
}

// ---------------------------------------------------------------------------
// Kernel B: MFMA pairwise Cauchy row/col sums — no LDS staging, and now
// ZERO GLOBAL ATOMICS (R2..R6 all shared ~532K contended cross-XCD T-atomics;
// this is the isolated variable). Block (ti,tj) stores its 128 row partials
// to Prow[tj][I..I+127] and 128 col partials to Pcol[ti][J..J+127] — plain
// coalesced stores to disjoint addresses. k_final reassembles T.
// Fragment loads straight from L2 (Fbf 2 MB resident); 2080 triangular
// 128x128 tiles; 4 waves (2x2), 4x4 frags of 16x16x32 bf16 each.
// Strict-upper mask on diagonal tiles; T excludes diagonal.
// ---------------------------------------------------------------------------
__global__ __launch_bounds__(256, 3) void k_pairwise(
        const __bf16* __restrict__ Fbf,
        const float* __restrict__ sq,
        float* __restrict__ Prow,
        float* __restrict__ Pcol) {
    // triangular decode: block b -> (ti, tj), tj >= ti
    int b = blockIdx.x;
    int ti = (int)floorf((129.0f - sqrtf(16641.0f - 8.0f * (float)b)) * 0.5f);
    while (ti * (129 - ti) / 2 > b) --ti;
    while ((ti + 1) * (128 - ti) / 2 <= b) ++ti;
    int tj = ti + (b - ti * (129 - ti) / 2);
    int I = ti * 128, J = tj * 128;
    bool diag = (ti == tj);

    __shared__ float rowAcc[128][2];
    __shared__ float colAcc[128][2];

    int t = threadIdx.x;
    int w = t >> 6;               // wave 0..3
    int l = t & 63;
    int wr = w >> 1, wc = w & 1;  // 2x2 wave grid, 64x64 quadrant each
    int low = l & 15, kb = l >> 4;

    const bf16x8* Fg = (const bf16x8*)Fbf;   // granule-indexed: row*16 + g

    // ---- K-loop: 4 steps of K=32, fragments straight from L2 ----
    f32x4 acc[4][4] = {};
#pragma unroll
    for (int s = 0; s < 4; ++s) {
        int g = s * 4 + kb;
        bf16x8 aF[4], bF[4];
#pragma unroll
        for (int fr = 0; fr < 4; ++fr)
            aF[fr] = Fg[(size_t)(I + wr * 64 + fr * 16 + low) * 16 + g];
#pragma unroll
        for (int fc = 0; fc < 4; ++fc)
            bF[fc] = Fg[(size_t)(J + wc * 64 + fc * 16 + low) * 16 + g];
#pragma unroll
        for (int fr = 0; fr < 4; ++fr)
#pragma unroll
            for (int fc = 0; fc < 4; ++fc)
                acc[fr][fc] = __builtin_amdgcn_mfma_f32_16x16x32_bf16(
                    aF[fr], bF[fc], acc[fr][fc], 0, 0, 0);
    }

    // ---- epilogue: Cauchy + row/col partial sums ----
    // C/D layout: col = low, row = kb*4 + reg (within each 16x16 fragment)
    float sqi[4][4], sqj[4];
#pragma unroll
    for (int fr = 0; fr < 4; ++fr)
#pragma unroll
        for (int r = 0; r < 4; ++r)
            sqi[fr][r] = sq[I + wr * 64 + fr * 16 + kb * 4 + r];
#pragma unroll
    for (int fc = 0; fc < 4; ++fc)
        sqj[fc] = sq[J + wc * 64 + fc * 16 + low];

    float rowPart[4][4] = {};
    float colPart[4] = {0.f, 0.f, 0.f, 0.f};
#define EPI(MASK)                                                              \
    _Pragma("unroll")                                                          \
    for (int fr = 0; fr < 4; ++fr) {                                           \
        _Pragma("unroll")                                                      \
        for (int fc = 0; fc < 4; ++fc) {                                       \
            _Pragma("unroll")                                                  \
            for (int r = 0; r < 4; ++r) {                                      \
                float d2 = sqi[fr][r] + sqj[fc] - 2.0f * acc[fr][fc][r];       \
                d2 = fmaxf(d2, 0.0f);                                          \
                float v = __builtin_amdgcn_rcpf(1.0f + d2);                    \
                if (MASK) {                                                    \
                    int R = wr * 64 + fr * 16 + kb * 4 + r;                    \
                    int C = wc * 64 + fc * 16 + low;                           \
                    v = (C > R) ? v : 0.0f;   /* strict upper on diag tile */  \
                }                                                              \
                rowPart[fr][r] += v;                                           \
                colPart[fc] += v;                                              \
            }                                                                  \
        }                                                                      \
    }
    if (diag) { EPI(true) } else { EPI(false) }
#undef EPI

    // row partials: reduce across the 16 lanes sharing a row (low)
#pragma unroll
    for (int fr = 0; fr < 4; ++fr)
#pragma unroll
        for (int r = 0; r < 4; ++r) {
            float x = rowPart[fr][r];
            x += __shfl_xor(x, 1);
            x += __shfl_xor(x, 2);
            x += __shfl_xor(x, 4);
            x += __shfl_xor(x, 8);
            if (low == 0)
                rowAcc[wr * 64 + fr * 16 + kb * 4 + r][wc] = x;
        }

    // col partials: reduce across the 4 lane-quads (kb)
#pragma unroll
    for (int fc = 0; fc < 4; ++fc) {
        float x = colPart[fc];
        x += __shfl_xor(x, 16);
        x += __shfl_xor(x, 32);
        if (kb == 0)
            colAcc[wc * 64 + fc * 16 + low][wr] = x;
    }
    __syncthreads();

    // contention-free partial stores (replaces all T atomics)
    if (t < 128) {
        Prow[(size_t)tj * N_TOTAL + I + t] = rowAcc[t][0] + rowAcc[t][1];
    } else {
        int c = t - 128;
        Pcol[(size_t)ti * N_TOTAL + J + c] = colAcc[c][0] + colAcc[c][1];
    }
}

// ---------------------------------------------------------------------------
// Kernel C: reassemble T per row from partials (exact ranges -> no zero-init),
// log, reduce; 32 blocks, one atomicAdd(out) each (32 total — negligible).
// Row i in strip s: T[i] = sum_{tj=s..63} Prow[tj][i] + sum_{ti=0..s} Pcol[ti][i].
// loss = [ sum 0.5*log(T_i) + sum posPart ] / b.
// ---------------------------------------------------------------------------
__global__ __launch_bounds__(256) void k_final(const float* __restrict__ Prow,
                                               const float* __restrict__ Pcol,
                                               const float* __restrict__ posPart,
                                               float* __restrict__ out) {
    int t = threadIdx.x;
    int i = blockIdx.x * 256 + t;
    int s = i >> 7;

    float Ti = 0.0f;
    for (int tj = s; tj < NTILES; ++tj) Ti += Prow[(size_t)tj * N_TOTAL + i];
    for (int ti = 0; ti <= s; ++ti)     Ti += Pcol[(size_t)ti * N_TOTAL + i];

    float v = 0.5f * logf(Ti);
    if (blockIdx.x == 0)
        for (int p = t; p < 1024; p += 256) v += posPart[p];

#pragma unroll
    for (int off = 32; off > 0; off >>= 1) v += __shfl_down(v, off);
    __shared__ float red[4];
    int w = t >> 6, l = t & 63;
    if (l == 0) red[w] = v;
    __syncthreads();
    if (t == 0) {
        float S = red[0] + red[1] + red[2] + red[3];
        atomicAdd(out, S / (float)BHALF);
    }
}

// ---------------------------------------------------------------------------
extern "C" void kernel_launch(void* const* d_in, const int* in_sizes, int n_in,
                              void* d_out, int out_size, void* d_ws, size_t ws_size,
                              hipStream_t stream) {
    const float* F = (const float*)d_in[0];
    float* out = (float*)d_out;

    char* ws = (char*)d_ws;
    __bf16* Fbf     = (__bf16*)ws;                                // 2 MB
    float*  sq      = (float*)(ws + (size_t)N_TOTAL * KDIM * 2);  // 8192 f
    float*  posPart = sq + N_TOTAL;                               // 1024 f
    float*  Prow    = posPart + 1024;                             // 64*8192 f = 2 MB
    float*  Pcol    = Prow + (size_t)NTILES * N_TOTAL;            // 2 MB

    hipMemsetAsync(out, 0, sizeof(float), stream);
    k_prep_pos<<<BHALF / 4, 256, 0, stream>>>(F, Fbf, sq, posPart);
    k_pairwise<<<NBLK, 256, 0, stream>>>(Fbf, sq, Prow, Pcol);
    k_final<<<N_TOTAL / 256, 256, 0, stream>>>(Prow, Pcol, posPart, out);
}